// Round 5
// baseline (202.649 us; speedup 1.0000x reference)
//
#include <hip/hip_runtime.h>
#include <math.h>

// Problem constants (fixed by setup_inputs: B=8, H=W=64, C=256, sr=8)
static constexpr int Bb  = 8;
static constexpr int Nn  = 4096;   // H*W
static constexpr int Cc  = 256;
static constexpr int Wd  = 64;     // image H == W
static constexpr int N1c = 256;    // 16x16 after 4x down
static constexpr int N2c = 64;     // 8x8 after 8x down

typedef __attribute__((ext_vector_type(8)))  short s16x8;   // 8 bf16 (4 VGPR)
typedef __attribute__((ext_vector_type(4)))  float f32x4v;  // MFMA acc

__device__ __forceinline__ unsigned short f2bf(float f) {
  unsigned u = __float_as_uint(f);
  unsigned r = (u + 0x7fffu + ((u >> 16) & 1u)) >> 16;   // RTN-even
  return (unsigned short)r;
}
__device__ __forceinline__ float bf2f(unsigned short h) {
  return __uint_as_float(((unsigned)h) << 16);
}

// ============ prepass: split 4 [256x256] fp32 weights into bf16 hi/lo (RTN) ========
__global__ __launch_bounds__(256)
void cvt4(const float* __restrict__ w0, const float* __restrict__ w1,
          const float* __restrict__ w2, const float* __restrict__ w3,
          unsigned short* __restrict__ hi, unsigned short* __restrict__ lo) {
  const int wsel = blockIdx.y;
  const float* w = wsel == 0 ? w0 : wsel == 1 ? w1 : wsel == 2 ? w2 : w3;
  const int i = (blockIdx.x * 256 + threadIdx.x) * 4;
  float4 v = *(const float4*)(w + i);
  unsigned short h0 = f2bf(v.x), h1 = f2bf(v.y), h2 = f2bf(v.z), h3 = f2bf(v.w);
  ushort4 hh = make_ushort4(h0, h1, h2, h3);
  ushort4 ll = make_ushort4(f2bf(v.x - bf2f(h0)), f2bf(v.y - bf2f(h1)),
                            f2bf(v.z - bf2f(h2)), f2bf(v.w - bf2f(h3)));
  *(ushort4*)(hi + (size_t)wsel * 65536 + i) = hh;
  *(ushort4*)(lo + (size_t)wsel * 65536 + i) = ll;
}

// ============ GEMM v3: LDS-free, BM=32, trunc-split A, 1-deep prefetch ==========
// Out[m,n] = sum_k A[m,k]*W[n,k] (+bias), 3-term split-bf16 MFMA.
// Block = 4 waves; block covers 32 rows x 256 cols; wave wid owns cols wid*64..+63.
// A split in-register via TRUNCATION (4 VALU/elem): ah=trunc(a), al=trunc(a-ah);
// residual <= 2^-16|a| (exact low-bits subtraction), dropped al*bl <= 2^-17.
// Fragments load straight from global; next k-step prefetched before MFMA block.
template<bool BIAS>
__global__ __launch_bounds__(256)
void gemm_v3(const float* __restrict__ A, const unsigned short* __restrict__ Wh,
             const unsigned short* __restrict__ Wl, const float* __restrict__ bias,
             float* __restrict__ Out) {
  const int tid  = threadIdx.x;
  const int lane = tid & 63, wid = tid >> 6;
  const int qi = lane & 15, g = lane >> 4;
  const int m0 = blockIdx.x * 32;

  const float*          Ab  = A  + (size_t)(m0 + qi) * 256 + g * 8;
  const unsigned short* WhB = Wh + (size_t)(wid * 64 + qi) * 256 + g * 8;
  const unsigned short* WlB = Wl + (size_t)(wid * 64 + qi) * 256 + g * 8;

  f32x4v acc[2][4] = {};   // [mt][nt]

#define LDK(k, aa, hh, ll)                                          \
  do {                                                              \
    aa[0] = *(const float4*)(Ab + (k));                             \
    aa[1] = *(const float4*)(Ab + (k) + 4);                         \
    aa[2] = *(const float4*)(Ab + 16 * 256 + (k));                  \
    aa[3] = *(const float4*)(Ab + 16 * 256 + (k) + 4);              \
    hh[0] = *(const uint4*)(WhB + (k));                             \
    hh[1] = *(const uint4*)(WhB + 16 * 256 + (k));                  \
    hh[2] = *(const uint4*)(WhB + 32 * 256 + (k));                  \
    hh[3] = *(const uint4*)(WhB + 48 * 256 + (k));                  \
    ll[0] = *(const uint4*)(WlB + (k));                             \
    ll[1] = *(const uint4*)(WlB + 16 * 256 + (k));                  \
    ll[2] = *(const uint4*)(WlB + 32 * 256 + (k));                  \
    ll[3] = *(const uint4*)(WlB + 48 * 256 + (k));                  \
  } while (0)

  float4 aC[4]; uint4 whC[4], wlC[4];
  LDK(0, aC, whC, wlC);

#pragma unroll
  for (int k0 = 0; k0 < 256; k0 += 32) {
    // ---- prefetch next k-step (wraps to 0 on last iter; harmless) ----
    float4 aN[4]; uint4 whN[4], wlN[4];
    const int kn = (k0 + 32) & 255;
    LDK(kn, aN, whN, wlN);
    // ---- truncation split: A fp32 -> ah, al bf16 (packed pairwise) ----
    s16x8 ah[2], al[2];
#pragma unroll
    for (int mt = 0; mt < 2; ++mt) {
      const float f[8] = {aC[2*mt].x, aC[2*mt].y, aC[2*mt].z, aC[2*mt].w,
                          aC[2*mt+1].x, aC[2*mt+1].y, aC[2*mt+1].z, aC[2*mt+1].w};
      unsigned hw[4], lw[4];
#pragma unroll
      for (int i = 0; i < 4; ++i) {
        const unsigned u0 = __float_as_uint(f[2*i]);
        const unsigned u1 = __float_as_uint(f[2*i+1]);
        hw[i] = (u0 >> 16) | (u1 & 0xffff0000u);
        const float l0 = f[2*i]   - __uint_as_float(u0 & 0xffff0000u);
        const float l1 = f[2*i+1] - __uint_as_float(u1 & 0xffff0000u);
        lw[i] = (__float_as_uint(l0) >> 16) | (__float_as_uint(l1) & 0xffff0000u);
      }
      uint4 th = make_uint4(hw[0], hw[1], hw[2], hw[3]);
      uint4 tl = make_uint4(lw[0], lw[1], lw[2], lw[3]);
      ah[mt] = *reinterpret_cast<s16x8*>(&th);
      al[mt] = *reinterpret_cast<s16x8*>(&tl);
    }
    // ---- MFMA: 2mt x 4nt x 3 terms ----
#pragma unroll
    for (int nt = 0; nt < 4; ++nt) {
      s16x8 bh = *reinterpret_cast<const s16x8*>(&whC[nt]);
      s16x8 bl = *reinterpret_cast<const s16x8*>(&wlC[nt]);
#pragma unroll
      for (int mt = 0; mt < 2; ++mt) {
        acc[mt][nt] = __builtin_amdgcn_mfma_f32_16x16x32_bf16(ah[mt], bh, acc[mt][nt], 0, 0, 0);
        acc[mt][nt] = __builtin_amdgcn_mfma_f32_16x16x32_bf16(ah[mt], bl, acc[mt][nt], 0, 0, 0);
        acc[mt][nt] = __builtin_amdgcn_mfma_f32_16x16x32_bf16(al[mt], bh, acc[mt][nt], 0, 0, 0);
      }
    }
    // ---- rotate (renamed by full unroll) ----
#pragma unroll
    for (int i = 0; i < 4; ++i) { aC[i] = aN[i]; whC[i] = whN[i]; wlC[i] = wlN[i]; }
  }
#undef LDK
  // ---- epilogue: C col=lane&15, row=(lane>>4)*4+reg ----
#pragma unroll
  for (int nt = 0; nt < 4; ++nt) {
    const int col = wid * 64 + nt * 16 + qi;
    const float bv = BIAS ? bias[col] : 0.f;
#pragma unroll
    for (int mt = 0; mt < 2; ++mt) {
#pragma unroll
      for (int r = 0; r < 4; ++r) {
        const int row = m0 + mt * 16 + g * 4 + r;
        Out[(size_t)row * 256 + col] = acc[mt][nt][r] + bv;
      }
    }
  }
}

// =============== fused: depthwise KSxKS stride-KS conv + bias + LN + exact GELU =======
template<int KS, int HO>
__global__ __launch_bounds__(256)
void down_ln_gelu(const float* __restrict__ x, const float* __restrict__ w,
                  const float* __restrict__ cb, const float* __restrict__ g,
                  const float* __restrict__ lb, float* __restrict__ xo) {
  const int b = blockIdx.y;
  const int n1 = blockIdx.x;
  const int i = n1 / HO, j = n1 % HO;
  const int c = threadIdx.x;
  const float* wc = w + c * KS * KS;
  const float* xb = x + ((size_t)b * Nn) * Cc + c;
  float acc = cb[c];
#pragma unroll
  for (int dy = 0; dy < KS; ++dy) {
#pragma unroll
    for (int dx = 0; dx < KS; ++dx) {
      int n = (i * KS + dy) * Wd + (j * KS + dx);
      acc = fmaf(wc[dy * KS + dx], xb[(size_t)n * Cc], acc);
    }
  }
  float s = acc, s2 = acc * acc;
#pragma unroll
  for (int off = 32; off; off >>= 1) {
    s  += __shfl_down(s, off);
    s2 += __shfl_down(s2, off);
  }
  __shared__ float rs[4], rq[4];
  if ((c & 63) == 0) { rs[c >> 6] = s; rq[c >> 6] = s2; }
  __syncthreads();
  float sum = rs[0] + rs[1] + rs[2] + rs[3];
  float sq  = rq[0] + rq[1] + rq[2] + rq[3];
  float mean = sum * (1.f / Cc);
  float var  = sq * (1.f / Cc) - mean * mean;
  float xn = (acc - mean) * rsqrtf(var + 1e-5f) * g[c] + lb[c];
  float gel = 0.5f * xn * (1.f + erff(xn * 0.70710678118654752440f));
  xo[((size_t)b * (HO * HO) + n1) * Cc + c] = gel;
}

// =============== v_new = v + dwconv3x3(v) + bias  (v = channels 128.. of kv) =========
template<int HS>
__global__ __launch_bounds__(128)
void vconv(const float* __restrict__ kv, const float* __restrict__ w,
           const float* __restrict__ bias, float* __restrict__ vo) {
  constexpr int NS = HS * HS;
  const int b = blockIdx.y;
  const int n1 = blockIdx.x;
  const int i = n1 / HS, j = n1 % HS;
  const int c = threadIdx.x;
  const float* vb = kv + ((size_t)b * NS) * Cc + 128 + c;
  const float* wc = w + c * 9;
  float acc = bias[c];
#pragma unroll
  for (int dy = 0; dy < 3; ++dy) {
    int ii = i + dy - 1;
    if (ii < 0 || ii >= HS) continue;
#pragma unroll
    for (int dx = 0; dx < 3; ++dx) {
      int jj = j + dx - 1;
      if (jj < 0 || jj >= HS) continue;
      acc = fmaf(wc[dy * 3 + dx], vb[(size_t)(ii * HS + jj) * Cc], acc);
    }
  }
  vo[((size_t)b * NS + n1) * 128 + c] = acc + vb[(size_t)n1 * Cc];
}

// =============== attention v3: MFMA, swapped QK^T, exact softmax =====================
template<int NS>
__global__ __launch_bounds__(256, 2)
void attn_mfma(float* __restrict__ qo, const float* __restrict__ kv,
               const float* __restrict__ vnew, const int branch) {
  constexpr int NT = NS / 16, NC = NS / 32, PS = NS + 8;
  constexpr float KC = 0.17677669529663688f * 1.4426950408889634f; // scale*log2e
  __shared__ unsigned short Klds[NS][40];
  constexpr int VB = NS * 36 * 4, PB = 4 * 16 * PS * 2;
  constexpr int USZ = (VB > PB) ? VB : PB;
  __shared__ __align__(16) char Ubuf[USZ];
  float (*vs)[36] = (float (*)[36])Ubuf;

  const int tid = threadIdx.x, lane = tid & 63, wid = tid >> 6;
  const int g = lane >> 4, qi = lane & 15;
  const int h = blockIdx.y, b = blockIdx.z;
  const int ck = h * 32;
  const int cq = branch * 128 + h * 32;

  for (int r = tid; r < NS; r += 256) {
    const float* kp = kv   + ((size_t)(b * NS + r)) * 256 + ck;
    const float* vp = vnew + ((size_t)(b * NS + r)) * 128 + ck;
    float kf[32];
#pragma unroll
    for (int i = 0; i < 8; ++i) *(float4*)&kf[i * 4] = *(const float4*)(kp + i * 4);
    unsigned kw[16];
#pragma unroll
    for (int i = 0; i < 16; ++i)
      kw[i] = f2bf(kf[2 * i]) | ((unsigned)f2bf(kf[2 * i + 1]) << 16);
#pragma unroll
    for (int i = 0; i < 4; ++i)
      *(uint4*)&Klds[r][i * 8] = make_uint4(kw[i*4], kw[i*4+1], kw[i*4+2], kw[i*4+3]);
#pragma unroll
    for (int i = 0; i < 8; ++i) *(float4*)&vs[r][i * 4] = *(const float4*)(vp + i * 4);
  }
  __syncthreads();

  s16x8 vt[2][NC];
#pragma unroll
  for (int dt = 0; dt < 2; ++dt)
#pragma unroll
    for (int c = 0; c < NC; ++c)
#pragma unroll
      for (int j = 0; j < 8; ++j)
        vt[dt][c][j] = (short)f2bf(vs[32 * c + 8 * g + j][16 * dt + qi]);
  __syncthreads();   // V region reused as P below

  unsigned short* Pw = (unsigned short*)Ubuf + (size_t)(wid * 16 + qi) * PS;

  for (int qt = 0; qt < 4; ++qt) {
    const int qrow = blockIdx.x * 256 + wid * 64 + qt * 16 + qi;
    float* qp = qo + ((size_t)b * Nn + qrow) * 256 + cq;
    float qf0[4], qf1[4];
    *(float4*)qf0 = *(const float4*)(qp + 8 * g);
    *(float4*)qf1 = *(const float4*)(qp + 8 * g + 4);
    s16x8 qfrag;
#pragma unroll
    for (int j = 0; j < 4; ++j) qfrag[j] = (short)f2bf(qf0[j]);
#pragma unroll
    for (int j = 0; j < 4; ++j) qfrag[4 + j] = (short)f2bf(qf1[j]);
    f32x4v s[NT];
#pragma unroll
    for (int t = 0; t < NT; ++t) {
      s16x8 kf = *(const s16x8*)&Klds[16 * t + qi][8 * g];
      s[t] = __builtin_amdgcn_mfma_f32_16x16x32_bf16(kf, qfrag,
                                                     (f32x4v){0.f, 0.f, 0.f, 0.f}, 0, 0, 0);
    }
    float m = s[0][0];
#pragma unroll
    for (int t = 0; t < NT; ++t)
      m = fmaxf(m, fmaxf(fmaxf(s[t][0], s[t][1]), fmaxf(s[t][2], s[t][3])));
    m = fmaxf(m, __shfl_xor(m, 16));
    m = fmaxf(m, __shfl_xor(m, 32));
    float l = 0.f;
#pragma unroll
    for (int t = 0; t < NT; ++t)
#pragma unroll
      for (int r = 0; r < 4; ++r) {
        float p = exp2f((s[t][r] - m) * KC);
        s[t][r] = p; l += p;
      }
    l += __shfl_xor(l, 16);
    l += __shfl_xor(l, 32);
#pragma unroll
    for (int t = 0; t < NT; ++t) {
      unsigned w0 = f2bf(s[t][0]) | ((unsigned)f2bf(s[t][1]) << 16);
      unsigned w1 = f2bf(s[t][2]) | ((unsigned)f2bf(s[t][3]) << 16);
      *(uint2*)&Pw[16 * t + 4 * g] = make_uint2(w0, w1);
    }
    f32x4v o0 = {0.f, 0.f, 0.f, 0.f}, o1 = {0.f, 0.f, 0.f, 0.f};
#pragma unroll
    for (int c = 0; c < NC; ++c) {
      s16x8 pf = *(const s16x8*)&Pw[32 * c + 8 * g];
      o0 = __builtin_amdgcn_mfma_f32_16x16x32_bf16(vt[0][c], pf, o0, 0, 0, 0);
      o1 = __builtin_amdgcn_mfma_f32_16x16x32_bf16(vt[1][c], pf, o1, 0, 0, 0);
    }
    const float inv = 1.f / l;
    float4 O0 = make_float4(o0[0] * inv, o0[1] * inv, o0[2] * inv, o0[3] * inv);
    float4 O1 = make_float4(o1[0] * inv, o1[1] * inv, o1[2] * inv, o1[3] * inv);
    *(float4*)(qp + 4 * g)      = O0;
    *(float4*)(qp + 16 + 4 * g) = O1;
  }
}

extern "C" void kernel_launch(void* const* d_in, const int* in_sizes, int n_in,
                              void* d_out, int out_size, void* d_ws, size_t ws_size,
                              hipStream_t stream) {
  const float* x      = (const float*)d_in[0];
  const float* q_w    = (const float*)d_in[1];
  const float* kv1_w  = (const float*)d_in[2];
  const float* kv2_w  = (const float*)d_in[3];
  const float* proj_w = (const float*)d_in[4];
  const float* proj_b = (const float*)d_in[5];
  const float* sr1_w  = (const float*)d_in[6];
  const float* sr1_b  = (const float*)d_in[7];
  const float* sr2_w  = (const float*)d_in[8];
  const float* sr2_b  = (const float*)d_in[9];
  const float* ln1_g  = (const float*)d_in[10];
  const float* ln1_b  = (const float*)d_in[11];
  const float* ln2_g  = (const float*)d_in[12];
  const float* ln2_b  = (const float*)d_in[13];
  const float* lc1_w  = (const float*)d_in[14];
  const float* lc1_b  = (const float*)d_in[15];
  const float* lc2_w  = (const float*)d_in[16];
  const float* lc2_b  = (const float*)d_in[17];
  float* out = (float*)d_out;
  float* ws  = (float*)d_ws;

  float* q   = ws;                                   // [B,N,C] (becomes o in-place)
  float* x1  = q   + (size_t)Bb * Nn  * Cc;
  float* kv1 = x1  + (size_t)Bb * N1c * Cc;
  float* vn1 = kv1 + (size_t)Bb * N1c * Cc;
  float* x2  = vn1 + (size_t)Bb * N1c * (Cc / 2);
  float* kv2 = x2  + (size_t)Bb * N2c * Cc;
  float* vn2 = kv2 + (size_t)Bb * N2c * Cc;
  float* fend = vn2 + (size_t)Bb * N2c * (Cc / 2);
  unsigned short* wh = (unsigned short*)fend;        // [4][65536] hi
  unsigned short* wl = wh + (size_t)4 * 65536;       // [4][65536] lo

  cvt4<<<dim3(64, 4), 256, 0, stream>>>(q_w, kv1_w, kv2_w, proj_w, wh, wl);
  gemm_v3<false><<<1024, 256, 0, stream>>>(x, wh, wl, nullptr, q);
  down_ln_gelu<4, 16><<<dim3(N1c, Bb), 256, 0, stream>>>(x, sr1_w, sr1_b, ln1_g, ln1_b, x1);
  down_ln_gelu<8, 8><<<dim3(N2c, Bb), 256, 0, stream>>>(x, sr2_w, sr2_b, ln2_g, ln2_b, x2);
  gemm_v3<false><<<64, 256, 0, stream>>>(x1, wh + 65536,     wl + 65536,     nullptr, kv1);
  gemm_v3<false><<<16, 256, 0, stream>>>(x2, wh + 2 * 65536, wl + 2 * 65536, nullptr, kv2);
  vconv<16><<<dim3(N1c, Bb), 128, 0, stream>>>(kv1, lc1_w, lc1_b, vn1);
  vconv<8> <<<dim3(N2c, Bb), 128, 0, stream>>>(kv2, lc2_w, lc2_b, vn2);
  attn_mfma<256><<<dim3(16, 4, Bb), 256, 0, stream>>>(q, kv1, vn1, 0);
  attn_mfma<64> <<<dim3(16, 4, Bb), 256, 0, stream>>>(q, kv2, vn2, 1);
  gemm_v3<true><<<1024, 256, 0, stream>>>(q, wh + 3 * 65536, wl + 3 * 65536, proj_b, out);
}

// Round 6
// 150.373 us; speedup vs baseline: 1.3476x; 1.3476x over previous
//
#include <hip/hip_runtime.h>
#include <math.h>

// Problem constants (fixed by setup_inputs: B=8, H=W=64, C=256, sr=8)
static constexpr int Bb  = 8;
static constexpr int Nn  = 4096;   // H*W
static constexpr int Cc  = 256;
static constexpr int Wd  = 64;     // image H == W
static constexpr int N1c = 256;    // 16x16 after 4x down
static constexpr int N2c = 64;     // 8x8 after 8x down

typedef __attribute__((ext_vector_type(8))) _Float16 f16x8;   // MFMA A/B frag
typedef __attribute__((ext_vector_type(4))) _Float16 f16x4;
typedef __attribute__((ext_vector_type(4))) float    f32x4v;  // MFMA acc

// ============ prepass: convert 4 [256x256] fp32 weights to fp16 (RN) ============
__global__ __launch_bounds__(256)
void cvt4f16(const float* __restrict__ w0, const float* __restrict__ w1,
             const float* __restrict__ w2, const float* __restrict__ w3,
             _Float16* __restrict__ wf) {
  const int wsel = blockIdx.y;
  const float* w = wsel == 0 ? w0 : wsel == 1 ? w1 : wsel == 2 ? w2 : w3;
  const int i = (blockIdx.x * 256 + threadIdx.x) * 4;
  float4 v = *(const float4*)(w + i);
  f16x4 o = {(_Float16)v.x, (_Float16)v.y, (_Float16)v.z, (_Float16)v.w};
  *(f16x4*)(wf + (size_t)wsel * 65536 + i) = o;
}

// ============ GEMM fp16: Out[m,n] = sum_k A[m,k]*W[n,k] (+bias) =================
// Single-term fp16 MFMA (error ~2e-4 at |w|~0.02, K=256). A fp32 converted
// in-register. Block = 4 waves = 64 rows x 256 cols; wave wid owns cols wid*64..+63.
// No LDS/barriers; W (128KB fp16) is L2-resident; A rows L1-shared across waves.
// 1-deep prefetch over the fully-unrolled 8-step k-loop.
template<bool BIAS>
__global__ __launch_bounds__(256)
void gemm_f16(const float* __restrict__ A, const _Float16* __restrict__ Wf,
              const float* __restrict__ bias, float* __restrict__ Out) {
  const int tid  = threadIdx.x;
  const int lane = tid & 63, wid = tid >> 6;
  const int qi = lane & 15, g = lane >> 4;
  const int m0 = blockIdx.x * 64;

  const float*    Ab = A  + (size_t)(m0 + qi) * 256 + g * 8;
  const _Float16* Wb = Wf + (size_t)(wid * 64 + qi) * 256 + g * 8;

  f32x4v acc[4][4] = {};   // [mt][nt]

#define LDK(k, aa, ww)                                              \
  do {                                                              \
    _Pragma("unroll")                                               \
    for (int mt = 0; mt < 4; ++mt) {                                \
      aa[2*mt]   = *(const float4*)(Ab + (size_t)mt*16*256 + (k));  \
      aa[2*mt+1] = *(const float4*)(Ab + (size_t)mt*16*256 + (k)+4);\
    }                                                               \
    _Pragma("unroll")                                               \
    for (int nt = 0; nt < 4; ++nt)                                  \
      ww[nt] = *(const f16x8*)(Wb + (size_t)nt*16*256 + (k));       \
  } while (0)

  float4 aC[8]; f16x8 wC[4];
  LDK(0, aC, wC);

#pragma unroll
  for (int k0 = 0; k0 < 256; k0 += 32) {
    float4 aN[8]; f16x8 wN[4];
    const int kn = (k0 + 32) & 255;   // wraps on last iter; harmless
    LDK(kn, aN, wN);
    // ---- convert A to fp16 frags ----
    f16x8 af[4];
#pragma unroll
    for (int mt = 0; mt < 4; ++mt) {
      const float f[8] = {aC[2*mt].x, aC[2*mt].y, aC[2*mt].z, aC[2*mt].w,
                          aC[2*mt+1].x, aC[2*mt+1].y, aC[2*mt+1].z, aC[2*mt+1].w};
#pragma unroll
      for (int j = 0; j < 8; ++j) af[mt][j] = (_Float16)f[j];
    }
    // ---- MFMA: 4mt x 4nt, single term ----
#pragma unroll
    for (int nt = 0; nt < 4; ++nt)
#pragma unroll
      for (int mt = 0; mt < 4; ++mt)
        acc[mt][nt] = __builtin_amdgcn_mfma_f32_16x16x32_f16(af[mt], wC[nt], acc[mt][nt], 0, 0, 0);
#pragma unroll
    for (int i = 0; i < 8; ++i) aC[i] = aN[i];
#pragma unroll
    for (int i = 0; i < 4; ++i) wC[i] = wN[i];
  }
#undef LDK
  // ---- epilogue: C col=lane&15, row=(lane>>4)*4+reg ----
#pragma unroll
  for (int nt = 0; nt < 4; ++nt) {
    const int col = wid * 64 + nt * 16 + qi;
    const float bv = BIAS ? bias[col] : 0.f;
#pragma unroll
    for (int mt = 0; mt < 4; ++mt) {
#pragma unroll
      for (int r = 0; r < 4; ++r) {
        const int row = m0 + mt * 16 + g * 4 + r;
        Out[(size_t)row * 256 + col] = acc[mt][nt][r] + bv;
      }
    }
  }
}

// =============== fused: depthwise KSxKS stride-KS conv + bias + LN + exact GELU =======
template<int KS, int HO>
__global__ __launch_bounds__(256)
void down_ln_gelu(const float* __restrict__ x, const float* __restrict__ w,
                  const float* __restrict__ cb, const float* __restrict__ g,
                  const float* __restrict__ lb, float* __restrict__ xo) {
  const int b = blockIdx.y;
  const int n1 = blockIdx.x;
  const int i = n1 / HO, j = n1 % HO;
  const int c = threadIdx.x;
  const float* wc = w + c * KS * KS;
  const float* xb = x + ((size_t)b * Nn) * Cc + c;
  float acc = cb[c];
#pragma unroll
  for (int dy = 0; dy < KS; ++dy) {
#pragma unroll
    for (int dx = 0; dx < KS; ++dx) {
      int n = (i * KS + dy) * Wd + (j * KS + dx);
      acc = fmaf(wc[dy * KS + dx], xb[(size_t)n * Cc], acc);
    }
  }
  float s = acc, s2 = acc * acc;
#pragma unroll
  for (int off = 32; off; off >>= 1) {
    s  += __shfl_down(s, off);
    s2 += __shfl_down(s2, off);
  }
  __shared__ float rs[4], rq[4];
  if ((c & 63) == 0) { rs[c >> 6] = s; rq[c >> 6] = s2; }
  __syncthreads();
  float sum = rs[0] + rs[1] + rs[2] + rs[3];
  float sq  = rq[0] + rq[1] + rq[2] + rq[3];
  float mean = sum * (1.f / Cc);
  float var  = sq * (1.f / Cc) - mean * mean;
  float xn = (acc - mean) * rsqrtf(var + 1e-5f) * g[c] + lb[c];
  float gel = 0.5f * xn * (1.f + erff(xn * 0.70710678118654752440f));
  xo[((size_t)b * (HO * HO) + n1) * Cc + c] = gel;
}

// =============== v_new = v + dwconv3x3(v) + bias  (v = channels 128.. of kv) =========
template<int HS>
__global__ __launch_bounds__(128)
void vconv(const float* __restrict__ kv, const float* __restrict__ w,
           const float* __restrict__ bias, float* __restrict__ vo) {
  constexpr int NS = HS * HS;
  const int b = blockIdx.y;
  const int n1 = blockIdx.x;
  const int i = n1 / HS, j = n1 % HS;
  const int c = threadIdx.x;
  const float* vb = kv + ((size_t)b * NS) * Cc + 128 + c;
  const float* wc = w + c * 9;
  float acc = bias[c];
#pragma unroll
  for (int dy = 0; dy < 3; ++dy) {
    int ii = i + dy - 1;
    if (ii < 0 || ii >= HS) continue;
#pragma unroll
    for (int dx = 0; dx < 3; ++dx) {
      int jj = j + dx - 1;
      if (jj < 0 || jj >= HS) continue;
      acc = fmaf(wc[dy * 3 + dx], vb[(size_t)(ii * HS + jj) * Cc], acc);
    }
  }
  vo[((size_t)b * NS + n1) * 128 + c] = acc + vb[(size_t)n1 * Cc];
}

// =============== attention v4: fp16 MFMA; V staged TRANSPOSED in LDS =================
// Block = 4 waves, 256 queries; grid (16, 4 h, 8 b). In-place q -> o.
// V^T staging kills the old 128-scalar-ds_read transpose: thread with key r writes
// Vt[d][r] (32 ds_write_b16); A-frags then read as contiguous ds_read_b128.
template<int NS>
__global__ __launch_bounds__(256, 2)
void attn_f16(float* __restrict__ qo, const float* __restrict__ kv,
              const float* __restrict__ vnew, const int branch) {
  constexpr int NT = NS / 16, NC = NS / 32, PS = NS + 8;
  constexpr float KC = 0.17677669529663688f * 1.4426950408889634f; // scale*log2e
  __shared__ _Float16 Klds[NS][40];        // [key][d]
  __shared__ _Float16 Vt[32][PS];          // [d][key]  (transposed!)
  __shared__ _Float16 Pl[64][PS];          // [wave*16+q][key]

  const int tid = threadIdx.x, lane = tid & 63, wid = tid >> 6;
  const int g = lane >> 4, qi = lane & 15;
  const int h = blockIdx.y, b = blockIdx.z;
  const int ck = h * 32;
  const int cq = branch * 128 + h * 32;

  // ---- stage K (row-major fp16) and V (transposed fp16) ----
  for (int r = tid; r < NS; r += 256) {
    const float* kp = kv   + ((size_t)(b * NS + r)) * 256 + ck;
    const float* vp = vnew + ((size_t)(b * NS + r)) * 128 + ck;
    float kf[32], vf[32];
#pragma unroll
    for (int i = 0; i < 8; ++i) {
      *(float4*)&kf[i * 4] = *(const float4*)(kp + i * 4);
      *(float4*)&vf[i * 4] = *(const float4*)(vp + i * 4);
    }
#pragma unroll
    for (int i = 0; i < 4; ++i) {
      f16x8 kw;
#pragma unroll
      for (int j = 0; j < 8; ++j) kw[j] = (_Float16)kf[8 * i + j];
      *(f16x8*)&Klds[r][8 * i] = kw;
    }
#pragma unroll
    for (int d = 0; d < 32; ++d) Vt[d][r] = (_Float16)vf[d];
  }
  __syncthreads();

  // ---- V^T A-frags from LDS (contiguous 16B reads) ----
  f16x8 vt[2][NC];
#pragma unroll
  for (int dt = 0; dt < 2; ++dt)
#pragma unroll
    for (int c = 0; c < NC; ++c)
      vt[dt][c] = *(const f16x8*)&Vt[16 * dt + qi][32 * c + 8 * g];

  _Float16* Pw = &Pl[wid * 16 + qi][0];

  for (int qt = 0; qt < 4; ++qt) {
    const int qrow = blockIdx.x * 256 + wid * 64 + qt * 16 + qi;
    float* qp = qo + ((size_t)b * Nn + qrow) * 256 + cq;
    float qf[8];
    *(float4*)&qf[0] = *(const float4*)(qp + 8 * g);
    *(float4*)&qf[4] = *(const float4*)(qp + 8 * g + 4);
    f16x8 qfrag;
#pragma unroll
    for (int j = 0; j < 8; ++j) qfrag[j] = (_Float16)qf[j];
    // ---- S^T tiles: s[t][r] = S[key=16t+4g+r][q=qi] ----
    f32x4v s[NT];
#pragma unroll
    for (int t = 0; t < NT; ++t) {
      f16x8 kf = *(const f16x8*)&Klds[16 * t + qi][8 * g];
      s[t] = __builtin_amdgcn_mfma_f32_16x16x32_f16(kf, qfrag,
                                                    (f32x4v){0.f, 0.f, 0.f, 0.f}, 0, 0, 0);
    }
    // ---- exact softmax (cross-lane over {qi, qi+16, qi+32, qi+48}) ----
    float m = s[0][0];
#pragma unroll
    for (int t = 0; t < NT; ++t)
      m = fmaxf(m, fmaxf(fmaxf(s[t][0], s[t][1]), fmaxf(s[t][2], s[t][3])));
    m = fmaxf(m, __shfl_xor(m, 16));
    m = fmaxf(m, __shfl_xor(m, 32));
    float l = 0.f;
#pragma unroll
    for (int t = 0; t < NT; ++t)
#pragma unroll
      for (int r = 0; r < 4; ++r) {
        float p = exp2f((s[t][r] - m) * KC);
        s[t][r] = p; l += p;
      }
    l += __shfl_xor(l, 16);
    l += __shfl_xor(l, 32);
    // ---- P -> fp16, per-(wave,q) LDS row ----
#pragma unroll
    for (int t = 0; t < NT; ++t) {
      f16x4 pw = {(_Float16)s[t][0], (_Float16)s[t][1],
                  (_Float16)s[t][2], (_Float16)s[t][3]};
      *(f16x4*)&Pw[16 * t + 4 * g] = pw;
    }
    // ---- PV: O^T accumulate over key chunks ----
    f32x4v o0 = {0.f, 0.f, 0.f, 0.f}, o1 = {0.f, 0.f, 0.f, 0.f};
#pragma unroll
    for (int c = 0; c < NC; ++c) {
      f16x8 pf = *(const f16x8*)&Pw[32 * c + 8 * g];
      o0 = __builtin_amdgcn_mfma_f32_16x16x32_f16(vt[0][c], pf, o0, 0, 0, 0);
      o1 = __builtin_amdgcn_mfma_f32_16x16x32_f16(vt[1][c], pf, o1, 0, 0, 0);
    }
    const float inv = 1.f / l;
    float4 O0 = make_float4(o0[0] * inv, o0[1] * inv, o0[2] * inv, o0[3] * inv);
    float4 O1 = make_float4(o1[0] * inv, o1[1] * inv, o1[2] * inv, o1[3] * inv);
    *(float4*)(qp + 4 * g)      = O0;   // d = 4g..4g+3
    *(float4*)(qp + 16 + 4 * g) = O1;   // d = 16+4g..16+4g+3
  }
}

extern "C" void kernel_launch(void* const* d_in, const int* in_sizes, int n_in,
                              void* d_out, int out_size, void* d_ws, size_t ws_size,
                              hipStream_t stream) {
  const float* x      = (const float*)d_in[0];
  const float* q_w    = (const float*)d_in[1];
  const float* kv1_w  = (const float*)d_in[2];
  const float* kv2_w  = (const float*)d_in[3];
  const float* proj_w = (const float*)d_in[4];
  const float* proj_b = (const float*)d_in[5];
  const float* sr1_w  = (const float*)d_in[6];
  const float* sr1_b  = (const float*)d_in[7];
  const float* sr2_w  = (const float*)d_in[8];
  const float* sr2_b  = (const float*)d_in[9];
  const float* ln1_g  = (const float*)d_in[10];
  const float* ln1_b  = (const float*)d_in[11];
  const float* ln2_g  = (const float*)d_in[12];
  const float* ln2_b  = (const float*)d_in[13];
  const float* lc1_w  = (const float*)d_in[14];
  const float* lc1_b  = (const float*)d_in[15];
  const float* lc2_w  = (const float*)d_in[16];
  const float* lc2_b  = (const float*)d_in[17];
  float* out = (float*)d_out;
  float* ws  = (float*)d_ws;

  float* q   = ws;                                   // [B,N,C] (becomes o in-place)
  float* x1  = q   + (size_t)Bb * Nn  * Cc;
  float* kv1 = x1  + (size_t)Bb * N1c * Cc;
  float* vn1 = kv1 + (size_t)Bb * N1c * Cc;
  float* x2  = vn1 + (size_t)Bb * N1c * (Cc / 2);
  float* kv2 = x2  + (size_t)Bb * N2c * Cc;
  float* vn2 = kv2 + (size_t)Bb * N2c * Cc;
  float* fend = vn2 + (size_t)Bb * N2c * (Cc / 2);
  _Float16* wf = (_Float16*)fend;                    // [4][65536] fp16 weights

  // 0) weights -> fp16: order = q_w, kv1_w, kv2_w, proj_w
  cvt4f16<<<dim3(64, 4), 256, 0, stream>>>(q_w, kv1_w, kv2_w, proj_w, wf);
  // 1) q = x @ q_w^T
  gemm_f16<false><<<512, 256, 0, stream>>>(x, wf, nullptr, q);
  // 2) spatial reductions + LN + GELU
  down_ln_gelu<4, 16><<<dim3(N1c, Bb), 256, 0, stream>>>(x, sr1_w, sr1_b, ln1_g, ln1_b, x1);
  down_ln_gelu<8, 8><<<dim3(N2c, Bb), 256, 0, stream>>>(x, sr2_w, sr2_b, ln2_g, ln2_b, x2);
  // 3) kv projections
  gemm_f16<false><<<32, 256, 0, stream>>>(x1, wf + 65536,     nullptr, kv1);
  gemm_f16<false><<<8,  256, 0, stream>>>(x2, wf + 2 * 65536, nullptr, kv2);
  // 4) v + local depthwise conv
  vconv<16><<<dim3(N1c, Bb), 128, 0, stream>>>(kv1, lc1_w, lc1_b, vn1);
  vconv<8> <<<dim3(N2c, Bb), 128, 0, stream>>>(kv2, lc2_w, lc2_b, vn2);
  // 5) attention (in-place on q)
  attn_f16<256><<<dim3(16, 4, Bb), 256, 0, stream>>>(q, kv1, vn1, 0);
  attn_f16<64> <<<dim3(16, 4, Bb), 256, 0, stream>>>(q, kv2, vn2, 1);
  // 6) projection + bias
  gemm_f16<true><<<512, 256, 0, stream>>>(q, wf + 3 * 65536, proj_b, out);
}

// Round 7
// 109.894 us; speedup vs baseline: 1.8440x; 1.3683x over previous
//
#include <hip/hip_runtime.h>
#include <math.h>

// Problem constants (fixed by setup_inputs: B=8, H=W=64, C=256, sr=8)
static constexpr int Bb  = 8;
static constexpr int Nn  = 4096;   // H*W
static constexpr int Cc  = 256;
static constexpr int Wd  = 64;     // image H == W
static constexpr int N1c = 256;    // 16x16 after 4x down
static constexpr int N2c = 64;     // 8x8 after 8x down

typedef __attribute__((ext_vector_type(8))) _Float16 f16x8;   // MFMA A/B frag
typedef __attribute__((ext_vector_type(4))) _Float16 f16x4;
typedef __attribute__((ext_vector_type(4))) float    f32x4v;  // MFMA acc

// ============ prepass: convert 4 [256x256] fp32 weights to fp16 (RN) ============
__global__ __launch_bounds__(256)
void cvt4f16(const float* __restrict__ w0, const float* __restrict__ w1,
             const float* __restrict__ w2, const float* __restrict__ w3,
             _Float16* __restrict__ wf) {
  const int wsel = blockIdx.y;
  const float* w = wsel == 0 ? w0 : wsel == 1 ? w1 : wsel == 2 ? w2 : w3;
  const int i = (blockIdx.x * 256 + threadIdx.x) * 4;
  float4 v = *(const float4*)(w + i);
  f16x4 o = {(_Float16)v.x, (_Float16)v.y, (_Float16)v.z, (_Float16)v.w};
  *(f16x4*)(wf + (size_t)wsel * 65536 + i) = o;
}

// ============ GEMM v5: LDS double-buffered fp16 MFMA ===========================
// Out[m,n] = sum_k A[m,k]*W[n,k] (+bias). BM=64, BN=256(full), BK=32, 4 waves;
// wave wid owns cols wid*64..+63 (4x4 16x16x32 frags). Reg-staged global->LDS
// with loads issued one compute-phase early (T14); 1 barrier/K-step.
// LDS rows padded to 40 halves (80B) - verified conflict-free for b128 r/w.
// A is fp32 (cvt in staging) or fp16 (direct); OUT fp32(+bias) or fp16.
template<bool A_HALF, bool OUT_HALF, bool BIAS>
__global__ __launch_bounds__(256)
void gemm_lds(const void* __restrict__ Ain, const _Float16* __restrict__ Wf,
              const float* __restrict__ bias, void* __restrict__ Outv) {
  __shared__ _Float16 Asl[2][64][40];
  __shared__ _Float16 Bsl[2][256][40];
  const int tid = threadIdx.x, lane = tid & 63, wid = tid >> 6;
  const int qi = lane & 15, g = lane >> 4;
  const int m0 = blockIdx.x * 64;
  const int ar = tid >> 2, ak = (tid & 3) * 8;   // A staging: row, k-offset

  const float*    pa32 = (const float*)Ain    + (size_t)(m0 + ar) * 256 + ak;
  const _Float16* pa16 = (const _Float16*)Ain + (size_t)(m0 + ar) * 256 + ak;
  const _Float16* pw   = Wf + (size_t)tid * 256;

  f32x4v acc[4][4] = {};   // [mt][nt]
  f16x8 rA; f16x8 rB[4];   // in-flight staging registers

#define LDREG(k0)                                                        \
  do {                                                                   \
    if (A_HALF) {                                                        \
      rA = *(const f16x8*)(pa16 + (k0));                                 \
    } else {                                                             \
      float4 t0 = *(const float4*)(pa32 + (k0));                         \
      float4 t1 = *(const float4*)(pa32 + (k0) + 4);                     \
      rA = (f16x8){(_Float16)t0.x, (_Float16)t0.y, (_Float16)t0.z,       \
                   (_Float16)t0.w, (_Float16)t1.x, (_Float16)t1.y,       \
                   (_Float16)t1.z, (_Float16)t1.w};                      \
    }                                                                    \
    _Pragma("unroll")                                                    \
    for (int i = 0; i < 4; ++i) rB[i] = *(const f16x8*)(pw + (k0) + i * 8); \
  } while (0)

#define DSWRITE(buf)                                                     \
  do {                                                                   \
    *(f16x8*)&Asl[buf][ar][ak] = rA;                                     \
    _Pragma("unroll")                                                    \
    for (int i = 0; i < 4; ++i) *(f16x8*)&Bsl[buf][tid][i * 8] = rB[i];  \
  } while (0)

  LDREG(0);
  DSWRITE(0);
  LDREG(32);                 // k-step 1 in flight across the barrier
  __syncthreads();

#pragma unroll
  for (int ks = 0; ks < 8; ++ks) {
    const int cur = ks & 1;
    if (ks < 7) DSWRITE(cur ^ 1);        // write k=ks+1 (regs loaded last iter)
    if (ks < 6) LDREG((ks + 2) * 32);    // issue k=ks+2 (hidden under compute)
    f16x8 af[4], bf[4];
#pragma unroll
    for (int mt = 0; mt < 4; ++mt)
      af[mt] = *(const f16x8*)&Asl[cur][mt * 16 + qi][g * 8];
#pragma unroll
    for (int nt = 0; nt < 4; ++nt)
      bf[nt] = *(const f16x8*)&Bsl[cur][wid * 64 + nt * 16 + qi][g * 8];
#pragma unroll
    for (int nt = 0; nt < 4; ++nt)
#pragma unroll
      for (int mt = 0; mt < 4; ++mt)
        acc[mt][nt] = __builtin_amdgcn_mfma_f32_16x16x32_f16(af[mt], bf[nt], acc[mt][nt], 0, 0, 0);
    __syncthreads();
  }
#undef LDREG
#undef DSWRITE

  // ---- epilogue: C col=lane&15, row=(lane>>4)*4+reg ----
#pragma unroll
  for (int nt = 0; nt < 4; ++nt) {
    const int col = wid * 64 + nt * 16 + qi;
    const float bv = BIAS ? bias[col] : 0.f;
#pragma unroll
    for (int mt = 0; mt < 4; ++mt) {
#pragma unroll
      for (int r = 0; r < 4; ++r) {
        const int row = m0 + mt * 16 + g * 4 + r;
        if (OUT_HALF)
          ((_Float16*)Outv)[(size_t)row * 256 + col] = (_Float16)acc[mt][nt][r];
        else
          ((float*)Outv)[(size_t)row * 256 + col] = acc[mt][nt][r] + bv;
      }
    }
  }
}

// =============== fused: depthwise KSxKS stride-KS conv + bias + LN + exact GELU =======
template<int KS, int HO>
__global__ __launch_bounds__(256)
void down_ln_gelu(const float* __restrict__ x, const float* __restrict__ w,
                  const float* __restrict__ cb, const float* __restrict__ g,
                  const float* __restrict__ lb, float* __restrict__ xo) {
  const int b = blockIdx.y;
  const int n1 = blockIdx.x;
  const int i = n1 / HO, j = n1 % HO;
  const int c = threadIdx.x;
  const float* wc = w + c * KS * KS;
  const float* xb = x + ((size_t)b * Nn) * Cc + c;
  float acc = cb[c];
#pragma unroll
  for (int dy = 0; dy < KS; ++dy) {
#pragma unroll
    for (int dx = 0; dx < KS; ++dx) {
      int n = (i * KS + dy) * Wd + (j * KS + dx);
      acc = fmaf(wc[dy * KS + dx], xb[(size_t)n * Cc], acc);
    }
  }
  float s = acc, s2 = acc * acc;
#pragma unroll
  for (int off = 32; off; off >>= 1) {
    s  += __shfl_down(s, off);
    s2 += __shfl_down(s2, off);
  }
  __shared__ float rs[4], rq[4];
  if ((c & 63) == 0) { rs[c >> 6] = s; rq[c >> 6] = s2; }
  __syncthreads();
  float sum = rs[0] + rs[1] + rs[2] + rs[3];
  float sq  = rq[0] + rq[1] + rq[2] + rq[3];
  float mean = sum * (1.f / Cc);
  float var  = sq * (1.f / Cc) - mean * mean;
  float xn = (acc - mean) * rsqrtf(var + 1e-5f) * g[c] + lb[c];
  float gel = 0.5f * xn * (1.f + erff(xn * 0.70710678118654752440f));
  xo[((size_t)b * (HO * HO) + n1) * Cc + c] = gel;
}

// =============== v_new = v + dwconv3x3(v) + bias  (v = channels 128.. of kv) =========
template<int HS>
__global__ __launch_bounds__(128)
void vconv(const float* __restrict__ kv, const float* __restrict__ w,
           const float* __restrict__ bias, float* __restrict__ vo) {
  constexpr int NS = HS * HS;
  const int b = blockIdx.y;
  const int n1 = blockIdx.x;
  const int i = n1 / HS, j = n1 % HS;
  const int c = threadIdx.x;
  const float* vb = kv + ((size_t)b * NS) * Cc + 128 + c;
  const float* wc = w + c * 9;
  float acc = bias[c];
#pragma unroll
  for (int dy = 0; dy < 3; ++dy) {
    int ii = i + dy - 1;
    if (ii < 0 || ii >= HS) continue;
#pragma unroll
    for (int dx = 0; dx < 3; ++dx) {
      int jj = j + dx - 1;
      if (jj < 0 || jj >= HS) continue;
      acc = fmaf(wc[dy * 3 + dx], vb[(size_t)(ii * HS + jj) * Cc], acc);
    }
  }
  vo[((size_t)b * NS + n1) * 128 + c] = acc + vb[(size_t)n1 * Cc];
}

// =============== attention v5: fp16 MFMA; fp16 q in / o out (in-place) ===============
// Block = 4 waves, 256 queries; grid (16, 4 h, 8 b). V staged TRANSPOSED in LDS.
template<int NS>
__global__ __launch_bounds__(256, 2)
void attn_f16(_Float16* __restrict__ qo, const float* __restrict__ kv,
              const float* __restrict__ vnew, const int branch) {
  constexpr int NT = NS / 16, NC = NS / 32, PS = NS + 8;
  constexpr float KC = 0.17677669529663688f * 1.4426950408889634f; // scale*log2e
  __shared__ _Float16 Klds[NS][40];        // [key][d]
  __shared__ _Float16 Vt[32][PS];          // [d][key]  (transposed)
  __shared__ _Float16 Pl[64][PS];          // [wave*16+q][key]

  const int tid = threadIdx.x, lane = tid & 63, wid = tid >> 6;
  const int g = lane >> 4, qi = lane & 15;
  const int h = blockIdx.y, b = blockIdx.z;
  const int ck = h * 32;
  const int cq = branch * 128 + h * 32;

  // ---- stage K (row-major fp16) and V (transposed fp16) ----
  for (int r = tid; r < NS; r += 256) {
    const float* kp = kv   + ((size_t)(b * NS + r)) * 256 + ck;
    const float* vp = vnew + ((size_t)(b * NS + r)) * 128 + ck;
    float kf[32], vf[32];
#pragma unroll
    for (int i = 0; i < 8; ++i) {
      *(float4*)&kf[i * 4] = *(const float4*)(kp + i * 4);
      *(float4*)&vf[i * 4] = *(const float4*)(vp + i * 4);
    }
#pragma unroll
    for (int i = 0; i < 4; ++i) {
      f16x8 kw;
#pragma unroll
      for (int j = 0; j < 8; ++j) kw[j] = (_Float16)kf[8 * i + j];
      *(f16x8*)&Klds[r][8 * i] = kw;
    }
#pragma unroll
    for (int d = 0; d < 32; ++d) Vt[d][r] = (_Float16)vf[d];
  }
  __syncthreads();

  // ---- V^T A-frags from LDS (contiguous 16B reads) ----
  f16x8 vt[2][NC];
#pragma unroll
  for (int dt = 0; dt < 2; ++dt)
#pragma unroll
    for (int c = 0; c < NC; ++c)
      vt[dt][c] = *(const f16x8*)&Vt[16 * dt + qi][32 * c + 8 * g];

  _Float16* Pw = &Pl[wid * 16 + qi][0];

  for (int qt = 0; qt < 4; ++qt) {
    const int qrow = blockIdx.x * 256 + wid * 64 + qt * 16 + qi;
    _Float16* qp = qo + ((size_t)b * Nn + qrow) * 256 + cq;
    f16x8 qfrag = *(const f16x8*)(qp + 8 * g);
    // ---- S^T tiles: s[t][r] = S[key=16t+4g+r][q=qi] ----
    f32x4v s[NT];
#pragma unroll
    for (int t = 0; t < NT; ++t) {
      f16x8 kf = *(const f16x8*)&Klds[16 * t + qi][8 * g];
      s[t] = __builtin_amdgcn_mfma_f32_16x16x32_f16(kf, qfrag,
                                                    (f32x4v){0.f, 0.f, 0.f, 0.f}, 0, 0, 0);
    }
    // ---- exact softmax (cross-lane over {qi, qi+16, qi+32, qi+48}) ----
    float m = s[0][0];
#pragma unroll
    for (int t = 0; t < NT; ++t)
      m = fmaxf(m, fmaxf(fmaxf(s[t][0], s[t][1]), fmaxf(s[t][2], s[t][3])));
    m = fmaxf(m, __shfl_xor(m, 16));
    m = fmaxf(m, __shfl_xor(m, 32));
    float l = 0.f;
#pragma unroll
    for (int t = 0; t < NT; ++t)
#pragma unroll
      for (int r = 0; r < 4; ++r) {
        float p = exp2f((s[t][r] - m) * KC);
        s[t][r] = p; l += p;
      }
    l += __shfl_xor(l, 16);
    l += __shfl_xor(l, 32);
    // ---- P -> fp16, per-(wave,q) LDS row ----
#pragma unroll
    for (int t = 0; t < NT; ++t) {
      f16x4 pw = {(_Float16)s[t][0], (_Float16)s[t][1],
                  (_Float16)s[t][2], (_Float16)s[t][3]};
      *(f16x4*)&Pw[16 * t + 4 * g] = pw;
    }
    // ---- PV: O^T accumulate over key chunks ----
    f32x4v o0 = {0.f, 0.f, 0.f, 0.f}, o1 = {0.f, 0.f, 0.f, 0.f};
#pragma unroll
    for (int c = 0; c < NC; ++c) {
      f16x8 pf = *(const f16x8*)&Pw[32 * c + 8 * g];
      o0 = __builtin_amdgcn_mfma_f32_16x16x32_f16(vt[0][c], pf, o0, 0, 0, 0);
      o1 = __builtin_amdgcn_mfma_f32_16x16x32_f16(vt[1][c], pf, o1, 0, 0, 0);
    }
    const float inv = 1.f / l;
    f16x4 O0 = {(_Float16)(o0[0] * inv), (_Float16)(o0[1] * inv),
                (_Float16)(o0[2] * inv), (_Float16)(o0[3] * inv)};
    f16x4 O1 = {(_Float16)(o1[0] * inv), (_Float16)(o1[1] * inv),
                (_Float16)(o1[2] * inv), (_Float16)(o1[3] * inv)};
    *(f16x4*)(qp + 4 * g)      = O0;   // d = 4g..4g+3
    *(f16x4*)(qp + 16 + 4 * g) = O1;   // d = 16+4g..16+4g+3
  }
}

extern "C" void kernel_launch(void* const* d_in, const int* in_sizes, int n_in,
                              void* d_out, int out_size, void* d_ws, size_t ws_size,
                              hipStream_t stream) {
  const float* x      = (const float*)d_in[0];
  const float* q_w    = (const float*)d_in[1];
  const float* kv1_w  = (const float*)d_in[2];
  const float* kv2_w  = (const float*)d_in[3];
  const float* proj_w = (const float*)d_in[4];
  const float* proj_b = (const float*)d_in[5];
  const float* sr1_w  = (const float*)d_in[6];
  const float* sr1_b  = (const float*)d_in[7];
  const float* sr2_w  = (const float*)d_in[8];
  const float* sr2_b  = (const float*)d_in[9];
  const float* ln1_g  = (const float*)d_in[10];
  const float* ln1_b  = (const float*)d_in[11];
  const float* ln2_g  = (const float*)d_in[12];
  const float* ln2_b  = (const float*)d_in[13];
  const float* lc1_w  = (const float*)d_in[14];
  const float* lc1_b  = (const float*)d_in[15];
  const float* lc2_w  = (const float*)d_in[16];
  const float* lc2_b  = (const float*)d_in[17];
  float* out = (float*)d_out;
  float* ws  = (float*)d_ws;

  // workspace layout (float units)
  float* x1  = ws;                                   // [B,N1,C]
  float* kv1 = x1  + (size_t)Bb * N1c * Cc;          // [B,N1,C]
  float* vn1 = kv1 + (size_t)Bb * N1c * Cc;          // [B,N1,128]
  float* x2  = vn1 + (size_t)Bb * N1c * (Cc / 2);    // [B,N2,C]
  float* kv2 = x2  + (size_t)Bb * N2c * Cc;          // [B,N2,C]
  float* vn2 = kv2 + (size_t)Bb * N2c * Cc;          // [B,N2,128]
  float* fend = vn2 + (size_t)Bb * N2c * (Cc / 2);
  _Float16* wf = (_Float16*)fend;                    // [4][65536] fp16 weights
  _Float16* qh = wf + (size_t)4 * 65536;             // [B,N,C] fp16 (q -> o in-place)

  // 0) weights -> fp16: order = q_w, kv1_w, kv2_w, proj_w
  cvt4f16<<<dim3(64, 4), 256, 0, stream>>>(q_w, kv1_w, kv2_w, proj_w, wf);
  // 1) q = x @ q_w^T  (fp16 out)
  gemm_lds<false, true, false><<<512, 256, 0, stream>>>(x, wf, nullptr, qh);
  // 2) spatial reductions + LN + GELU
  down_ln_gelu<4, 16><<<dim3(N1c, Bb), 256, 0, stream>>>(x, sr1_w, sr1_b, ln1_g, ln1_b, x1);
  down_ln_gelu<8, 8><<<dim3(N2c, Bb), 256, 0, stream>>>(x, sr2_w, sr2_b, ln2_g, ln2_b, x2);
  // 3) kv projections (fp32 out)
  gemm_lds<false, false, false><<<32, 256, 0, stream>>>(x1, wf + 65536,     nullptr, kv1);
  gemm_lds<false, false, false><<<8,  256, 0, stream>>>(x2, wf + 2 * 65536, nullptr, kv2);
  // 4) v + local depthwise conv
  vconv<16><<<dim3(N1c, Bb), 128, 0, stream>>>(kv1, lc1_w, lc1_b, vn1);
  vconv<8> <<<dim3(N2c, Bb), 128, 0, stream>>>(kv2, lc2_w, lc2_b, vn2);
  // 5) attention (in-place on fp16 q)
  attn_f16<256><<<dim3(16, 4, Bb), 256, 0, stream>>>(qh, kv1, vn1, 0);
  attn_f16<64> <<<dim3(16, 4, Bb), 256, 0, stream>>>(qh, kv2, vn2, 1);
  // 6) projection + bias (fp16 A, fp32 out)
  gemm_lds<true, false, true><<<512, 256, 0, stream>>>(qh, wf + 3 * 65536, proj_b, out);
}

// Round 8
// 89.518 us; speedup vs baseline: 2.2638x; 1.2276x over previous
//
#include <hip/hip_runtime.h>
#include <math.h>

// Problem constants (fixed by setup_inputs: B=8, H=W=64, C=256, sr=8)
static constexpr int Bb  = 8;
static constexpr int Nn  = 4096;   // H*W
static constexpr int Cc  = 256;
static constexpr int N1c = 256;    // 16x16 after 4x down
static constexpr int N2c = 64;     // 8x8 after 8x down

typedef __attribute__((ext_vector_type(8))) _Float16 f16x8;   // MFMA A/B frag
typedef __attribute__((ext_vector_type(4))) _Float16 f16x4;
typedef __attribute__((ext_vector_type(4))) float    f32x4v;  // MFMA acc

// ============ prepass: weights->fp16 + transpose conv weights to [tap][C] ========
// blocks 0..255: 4x[256x256] fp32 -> fp16. blocks 256..335: wt1[16][256], wt2[64][256].
__global__ __launch_bounds__(256)
void prep(const float* __restrict__ w0, const float* __restrict__ w1,
          const float* __restrict__ w2, const float* __restrict__ w3,
          const float* __restrict__ sr1w, const float* __restrict__ sr2w,
          _Float16* __restrict__ wf, float* __restrict__ wt1, float* __restrict__ wt2) {
  const int bid = blockIdx.x, c = threadIdx.x;
  if (bid < 256) {
    const int wsel = bid >> 6;
    const float* w = wsel == 0 ? w0 : wsel == 1 ? w1 : wsel == 2 ? w2 : w3;
    const int i = ((bid & 63) * 256 + c) * 4;
    float4 v = *(const float4*)(w + i);
    f16x4 o = {(_Float16)v.x, (_Float16)v.y, (_Float16)v.z, (_Float16)v.w};
    *(f16x4*)(wf + (size_t)wsel * 65536 + i) = o;
  } else {
    const int row = bid - 256;           // 0..79
    if (row < 16) wt1[row * 256 + c] = sr1w[c * 16 + row];
    else { const int q = row - 16; wt2[q * 256 + c] = sr2w[c * 64 + q]; }
  }
}

// ============ GEMM body: LDS double-buffered fp16 MFMA ==========================
// Out[m,n] = sum_k A[m,k]*W[n,k] (+bias). BM=64, BN=256(full), BK=32, 4 waves.
// Reg-staged global->LDS, loads one phase early; 1 barrier/K-step.
template<bool A_HALF, bool OUT_HALF, bool BIAS>
__device__ __forceinline__
void gemm_body(const void* __restrict__ Ain, const _Float16* __restrict__ Wf,
               const float* __restrict__ bias, void* __restrict__ Outv, int m0) {
  __shared__ _Float16 Asl[2][64][40];
  __shared__ _Float16 Bsl[2][256][40];
  const int tid = threadIdx.x, lane = tid & 63, wid = tid >> 6;
  const int qi = lane & 15, g = lane >> 4;
  const int ar = tid >> 2, ak = (tid & 3) * 8;

  const float*    pa32 = (const float*)Ain    + (size_t)(m0 + ar) * 256 + ak;
  const _Float16* pa16 = (const _Float16*)Ain + (size_t)(m0 + ar) * 256 + ak;
  const _Float16* pw   = Wf + (size_t)tid * 256;

  f32x4v acc[4][4] = {};
  f16x8 rA; f16x8 rB[4];

#define LDREG(k0)                                                        \
  do {                                                                   \
    if (A_HALF) {                                                        \
      rA = *(const f16x8*)(pa16 + (k0));                                 \
    } else {                                                             \
      float4 t0 = *(const float4*)(pa32 + (k0));                         \
      float4 t1 = *(const float4*)(pa32 + (k0) + 4);                     \
      rA = (f16x8){(_Float16)t0.x, (_Float16)t0.y, (_Float16)t0.z,       \
                   (_Float16)t0.w, (_Float16)t1.x, (_Float16)t1.y,       \
                   (_Float16)t1.z, (_Float16)t1.w};                      \
    }                                                                    \
    _Pragma("unroll")                                                    \
    for (int i = 0; i < 4; ++i) rB[i] = *(const f16x8*)(pw + (k0) + i * 8); \
  } while (0)

#define DSWRITE(buf)                                                     \
  do {                                                                   \
    *(f16x8*)&Asl[buf][ar][ak] = rA;                                     \
    _Pragma("unroll")                                                    \
    for (int i = 0; i < 4; ++i) *(f16x8*)&Bsl[buf][tid][i * 8] = rB[i];  \
  } while (0)

  LDREG(0);
  DSWRITE(0);
  LDREG(32);
  __syncthreads();

#pragma unroll
  for (int ks = 0; ks < 8; ++ks) {
    const int cur = ks & 1;
    if (ks < 7) DSWRITE(cur ^ 1);
    if (ks < 6) LDREG((ks + 2) * 32);
    f16x8 af[4], bf[4];
#pragma unroll
    for (int mt = 0; mt < 4; ++mt)
      af[mt] = *(const f16x8*)&Asl[cur][mt * 16 + qi][g * 8];
#pragma unroll
    for (int nt = 0; nt < 4; ++nt)
      bf[nt] = *(const f16x8*)&Bsl[cur][wid * 64 + nt * 16 + qi][g * 8];
#pragma unroll
    for (int nt = 0; nt < 4; ++nt)
#pragma unroll
      for (int mt = 0; mt < 4; ++mt)
        acc[mt][nt] = __builtin_amdgcn_mfma_f32_16x16x32_f16(af[mt], bf[nt], acc[mt][nt], 0, 0, 0);
    __syncthreads();
  }
#undef LDREG
#undef DSWRITE

#pragma unroll
  for (int nt = 0; nt < 4; ++nt) {
    const int col = wid * 64 + nt * 16 + qi;
    const float bv = BIAS ? bias[col] : 0.f;
#pragma unroll
    for (int mt = 0; mt < 4; ++mt) {
#pragma unroll
      for (int r = 0; r < 4; ++r) {
        const int row = m0 + mt * 16 + g * 4 + r;
        if (OUT_HALF)
          ((_Float16*)Outv)[(size_t)row * 256 + col] = (_Float16)acc[mt][nt][r];
        else
          ((float*)Outv)[(size_t)row * 256 + col] = acc[mt][nt][r] + bv;
      }
    }
  }
}

template<bool A_HALF, bool OUT_HALF, bool BIAS>
__global__ __launch_bounds__(256)
void gemm_lds(const void* __restrict__ Ain, const _Float16* __restrict__ Wf,
              const float* __restrict__ bias, void* __restrict__ Outv) {
  gemm_body<A_HALF, OUT_HALF, BIAS>(Ain, Wf, bias, Outv, blockIdx.x * 64);
}

// merged kv1 + kv2 projection: blocks 0..31 -> kv1 (2048 rows), 32..39 -> kv2 (512)
__global__ __launch_bounds__(256)
void gemm_kv(const _Float16* __restrict__ A1, const _Float16* __restrict__ A2,
             const _Float16* __restrict__ W1, const _Float16* __restrict__ W2,
             _Float16* __restrict__ O1, _Float16* __restrict__ O2) {
  const int bx = blockIdx.x;
  if (bx < 32) gemm_body<true, true, false>(A1, W1, nullptr, O1, bx * 64);
  else         gemm_body<true, true, false>(A2, W2, nullptr, O2, (bx - 32) * 64);
}

// ============ fused: BOTH spatial reductions + bias + LN + exact GELU ===========
// One block per 8x8 stride-8 window (branch2 pixel); contains 4 branch1 pixels.
// x read ONCE. Weights pre-transposed: wt1[tap][C], wt2[tap][C] (coalesced).
__global__ __launch_bounds__(256)
void down2_ln_gelu(const float* __restrict__ x,
                   const float* __restrict__ wt1, const float* __restrict__ b1,
                   const float* __restrict__ g1, const float* __restrict__ lb1,
                   const float* __restrict__ wt2, const float* __restrict__ b2,
                   const float* __restrict__ g2, const float* __restrict__ lb2,
                   _Float16* __restrict__ x1o, _Float16* __restrict__ x2o) {
  const int b = blockIdx.y;
  const int n2 = blockIdx.x;            // 0..63
  const int i2 = n2 >> 3, j2 = n2 & 7;
  const int c = threadIdx.x;
  const int lane = c & 63, wave = c >> 6;
  const float* xb = x + ((size_t)b * Nn) * Cc + c;

  // preload 16 branch1 weights (reused 4x each)
  float w1r[16];
#pragma unroll
  for (int t = 0; t < 16; ++t) w1r[t] = wt1[t * 256 + c];

  float a2 = b2[c];
  float a1[2][2] = {{b1[c], b1[c]}, {b1[c], b1[c]}};
#pragma unroll
  for (int dy = 0; dy < 8; ++dy) {
    float vr[8], w2r[8];
#pragma unroll
    for (int dx = 0; dx < 8; ++dx) {
      vr[dx]  = xb[(size_t)((8 * i2 + dy) * 64 + 8 * j2 + dx) * 256];
      w2r[dx] = wt2[(dy * 8 + dx) * 256 + c];
    }
#pragma unroll
    for (int dx = 0; dx < 8; ++dx) {
      a2 = fmaf(w2r[dx], vr[dx], a2);
      a1[dy >> 2][dx >> 2] = fmaf(w1r[(dy & 3) * 4 + (dx & 3)], vr[dx],
                                  a1[dy >> 2][dx >> 2]);
    }
  }

  // 5 LayerNorms over C=256
  float vals[5] = {a2, a1[0][0], a1[0][1], a1[1][0], a1[1][1]};
  __shared__ float redS[4][5], redQ[4][5];
  float sum[5], sq[5];
#pragma unroll
  for (int p = 0; p < 5; ++p) {
    float s = vals[p], q2 = vals[p] * vals[p];
#pragma unroll
    for (int off = 1; off < 64; off <<= 1) {
      s  += __shfl_xor(s, off);
      q2 += __shfl_xor(q2, off);
    }
    if (lane == 0) { redS[wave][p] = s; redQ[wave][p] = q2; }
  }
  __syncthreads();
#pragma unroll
  for (int p = 0; p < 5; ++p) {
    sum[p] = redS[0][p] + redS[1][p] + redS[2][p] + redS[3][p];
    sq[p]  = redQ[0][p] + redQ[1][p] + redQ[2][p] + redQ[3][p];
  }
#pragma unroll
  for (int p = 0; p < 5; ++p) {
    const float mean = sum[p] * (1.f / Cc);
    const float var  = sq[p] * (1.f / Cc) - mean * mean;
    const float gg = (p == 0) ? g2[c] : g1[c];
    const float bb = (p == 0) ? lb2[c] : lb1[c];
    const float xn = (vals[p] - mean) * rsqrtf(var + 1e-5f) * gg + bb;
    const float gel = 0.5f * xn * (1.f + erff(xn * 0.70710678118654752440f));
    if (p == 0) {
      x2o[((size_t)b * N2c + n2) * 256 + c] = (_Float16)gel;
    } else {
      const int a = (p - 1) >> 1, bbx = (p - 1) & 1;
      const int n1 = (2 * i2 + a) * 16 + (2 * j2 + bbx);
      x1o[((size_t)b * N1c + n1) * 256 + c] = (_Float16)gel;
    }
  }
}

// =============== v_new = v + dwconv3x3(v) + bias (fp16 kv in, fp16 vn out) ==========
template<int HS>
__device__ __forceinline__
void vconv_body(const _Float16* __restrict__ kv, const float* __restrict__ w,
                const float* __restrict__ bias, _Float16* __restrict__ vo,
                int b, int n1, int c) {
  constexpr int NS = HS * HS;
  const int i = n1 / HS, j = n1 % HS;
  const _Float16* vb = kv + ((size_t)b * NS) * 256 + 128 + c;
  const float* wc = w + c * 9;
  float acc = bias[c];
#pragma unroll
  for (int dy = 0; dy < 3; ++dy) {
    const int ii = i + dy - 1;
    if (ii < 0 || ii >= HS) continue;
#pragma unroll
    for (int dx = 0; dx < 3; ++dx) {
      const int jj = j + dx - 1;
      if (jj < 0 || jj >= HS) continue;
      acc = fmaf(wc[dy * 3 + dx], (float)vb[(size_t)(ii * HS + jj) * 256], acc);
    }
  }
  vo[((size_t)b * NS + n1) * 128 + c] = (_Float16)(acc + (float)vb[(size_t)n1 * 256]);
}

__global__ __launch_bounds__(128)
void vconv2(const _Float16* __restrict__ kv1, const _Float16* __restrict__ kv2,
            const float* __restrict__ w1, const float* __restrict__ b1,
            const float* __restrict__ w2, const float* __restrict__ b2,
            _Float16* __restrict__ vn1, _Float16* __restrict__ vn2) {
  const int bid = blockIdx.x, c = threadIdx.x;
  if (bid < 2048) vconv_body<16>(kv1, w1, b1, vn1, bid >> 8, bid & 255, c);
  else { const int t = bid - 2048; vconv_body<8>(kv2, w2, b2, vn2, t >> 6, t & 63, c); }
}

// =============== attention: fp16 MFMA; fp16 q/k/v in, fp16 o out (in-place) ==========
// Block = 4 waves, 256 queries; grid (16, 4 h, 8 b). V staged TRANSPOSED in LDS.
template<int NS>
__global__ __launch_bounds__(256, 2)
void attn_f16(_Float16* __restrict__ qo, const _Float16* __restrict__ kv,
              const _Float16* __restrict__ vnew, const int branch) {
  constexpr int NT = NS / 16, NC = NS / 32, PS = NS + 8;
  constexpr float KC = 0.17677669529663688f * 1.4426950408889634f; // scale*log2e
  __shared__ _Float16 Klds[NS][40];        // [key][d]
  __shared__ _Float16 Vt[32][PS];          // [d][key]
  __shared__ _Float16 Pl[64][PS];          // [wave*16+q][key]

  const int tid = threadIdx.x, lane = tid & 63, wid = tid >> 6;
  const int g = lane >> 4, qi = lane & 15;
  const int h = blockIdx.y, b = blockIdx.z;
  const int ck = h * 32;
  const int cq = branch * 128 + h * 32;

  for (int r = tid; r < NS; r += 256) {
    const _Float16* kp = kv   + ((size_t)(b * NS + r)) * 256 + ck;
    const _Float16* vp = vnew + ((size_t)(b * NS + r)) * 128 + ck;
#pragma unroll
    for (int i = 0; i < 4; ++i)
      *(f16x8*)&Klds[r][8 * i] = *(const f16x8*)(kp + 8 * i);
    _Float16 va[32];
#pragma unroll
    for (int i = 0; i < 4; ++i)
      *(f16x8*)&va[8 * i] = *(const f16x8*)(vp + 8 * i);
#pragma unroll
    for (int d = 0; d < 32; ++d) Vt[d][r] = va[d];
  }
  __syncthreads();

  f16x8 vt[2][NC];
#pragma unroll
  for (int dt = 0; dt < 2; ++dt)
#pragma unroll
    for (int c = 0; c < NC; ++c)
      vt[dt][c] = *(const f16x8*)&Vt[16 * dt + qi][32 * c + 8 * g];

  _Float16* Pw = &Pl[wid * 16 + qi][0];

  for (int qt = 0; qt < 4; ++qt) {
    const int qrow = blockIdx.x * 256 + wid * 64 + qt * 16 + qi;
    _Float16* qp = qo + ((size_t)b * Nn + qrow) * 256 + cq;
    f16x8 qfrag = *(const f16x8*)(qp + 8 * g);
    f32x4v s[NT];
#pragma unroll
    for (int t = 0; t < NT; ++t) {
      f16x8 kf = *(const f16x8*)&Klds[16 * t + qi][8 * g];
      s[t] = __builtin_amdgcn_mfma_f32_16x16x32_f16(kf, qfrag,
                                                    (f32x4v){0.f, 0.f, 0.f, 0.f}, 0, 0, 0);
    }
    float m = s[0][0];
#pragma unroll
    for (int t = 0; t < NT; ++t)
      m = fmaxf(m, fmaxf(fmaxf(s[t][0], s[t][1]), fmaxf(s[t][2], s[t][3])));
    m = fmaxf(m, __shfl_xor(m, 16));
    m = fmaxf(m, __shfl_xor(m, 32));
    float l = 0.f;
#pragma unroll
    for (int t = 0; t < NT; ++t)
#pragma unroll
      for (int r = 0; r < 4; ++r) {
        float p = exp2f((s[t][r] - m) * KC);
        s[t][r] = p; l += p;
      }
    l += __shfl_xor(l, 16);
    l += __shfl_xor(l, 32);
#pragma unroll
    for (int t = 0; t < NT; ++t) {
      f16x4 pw = {(_Float16)s[t][0], (_Float16)s[t][1],
                  (_Float16)s[t][2], (_Float16)s[t][3]};
      *(f16x4*)&Pw[16 * t + 4 * g] = pw;
    }
    f32x4v o0 = {0.f, 0.f, 0.f, 0.f}, o1 = {0.f, 0.f, 0.f, 0.f};
#pragma unroll
    for (int c = 0; c < NC; ++c) {
      f16x8 pf = *(const f16x8*)&Pw[32 * c + 8 * g];
      o0 = __builtin_amdgcn_mfma_f32_16x16x32_f16(vt[0][c], pf, o0, 0, 0, 0);
      o1 = __builtin_amdgcn_mfma_f32_16x16x32_f16(vt[1][c], pf, o1, 0, 0, 0);
    }
    const float inv = 1.f / l;
    f16x4 O0 = {(_Float16)(o0[0] * inv), (_Float16)(o0[1] * inv),
                (_Float16)(o0[2] * inv), (_Float16)(o0[3] * inv)};
    f16x4 O1 = {(_Float16)(o1[0] * inv), (_Float16)(o1[1] * inv),
                (_Float16)(o1[2] * inv), (_Float16)(o1[3] * inv)};
    *(f16x4*)(qp + 4 * g)      = O0;
    *(f16x4*)(qp + 16 + 4 * g) = O1;
  }
}

extern "C" void kernel_launch(void* const* d_in, const int* in_sizes, int n_in,
                              void* d_out, int out_size, void* d_ws, size_t ws_size,
                              hipStream_t stream) {
  const float* x      = (const float*)d_in[0];
  const float* q_w    = (const float*)d_in[1];
  const float* kv1_w  = (const float*)d_in[2];
  const float* kv2_w  = (const float*)d_in[3];
  const float* proj_w = (const float*)d_in[4];
  const float* proj_b = (const float*)d_in[5];
  const float* sr1_w  = (const float*)d_in[6];
  const float* sr1_b  = (const float*)d_in[7];
  const float* sr2_w  = (const float*)d_in[8];
  const float* sr2_b  = (const float*)d_in[9];
  const float* ln1_g  = (const float*)d_in[10];
  const float* ln1_b  = (const float*)d_in[11];
  const float* ln2_g  = (const float*)d_in[12];
  const float* ln2_b  = (const float*)d_in[13];
  const float* lc1_w  = (const float*)d_in[14];
  const float* lc1_b  = (const float*)d_in[15];
  const float* lc2_w  = (const float*)d_in[16];
  const float* lc2_b  = (const float*)d_in[17];
  float* out = (float*)d_out;

  // workspace layout
  char* wsb = (char*)d_ws;
  _Float16* wf   = (_Float16*)wsb;                       // [4][65536]
  _Float16* qh   = wf + (size_t)4 * 65536;               // [B*N][256]
  _Float16* x1h  = qh + (size_t)Bb * Nn * Cc;            // [B*N1][256]
  _Float16* x2h  = x1h + (size_t)Bb * N1c * Cc;          // [B*N2][256]
  _Float16* kv1h = x2h + (size_t)Bb * N2c * Cc;          // [B*N1][256]
  _Float16* kv2h = kv1h + (size_t)Bb * N1c * Cc;         // [B*N2][256]
  _Float16* vn1h = kv2h + (size_t)Bb * N2c * Cc;         // [B*N1][128]
  _Float16* vn2h = vn1h + (size_t)Bb * N1c * 128;        // [B*N2][128]
  float* wt1 = (float*)(vn2h + (size_t)Bb * N2c * 128);  // [16][256]
  float* wt2 = wt1 + 16 * 256;                           // [64][256]

  // 0) prepass: weights->fp16 (order q, kv1, kv2, proj) + conv-weight transposes
  prep<<<336, 256, 0, stream>>>(q_w, kv1_w, kv2_w, proj_w, sr1_w, sr2_w, wf, wt1, wt2);
  // 1) q = x @ q_w^T  (fp16 out)
  gemm_lds<false, true, false><<<512, 256, 0, stream>>>(x, wf, nullptr, qh);
  // 2) fused dual spatial reduction + LN + GELU (x read once)
  down2_ln_gelu<<<dim3(64, Bb), 256, 0, stream>>>(x, wt1, sr1_b, ln1_g, ln1_b,
                                                  wt2, sr2_b, ln2_g, ln2_b, x1h, x2h);
  // 3) kv projections (merged, fp16 out)
  gemm_kv<<<40, 256, 0, stream>>>(x1h, x2h, wf + 65536, wf + 2 * 65536, kv1h, kv2h);
  // 4) v + local depthwise conv (merged)
  vconv2<<<2560, 128, 0, stream>>>(kv1h, kv2h, lc1_w, lc1_b, lc2_w, lc2_b, vn1h, vn2h);
  // 5) attention (in-place on fp16 q)
  attn_f16<256><<<dim3(16, 4, Bb), 256, 0, stream>>>(qh, kv1h, vn1h, 0);
  attn_f16<64> <<<dim3(16, 4, Bb), 256, 0, stream>>>(qh, kv2h, vn2h, 1);
  // 6) projection + bias (fp16 A, fp32 out)
  gemm_lds<true, false, true><<<512, 256, 0, stream>>>(qh, wf + 3 * 65536, proj_b, out);
}